// Round 7
// baseline (118.658 us; speedup 1.0000x reference)
//
#include <hip/hip_runtime.h>
#include <math.h>

#define NB 8192
#define DK 128
#define SPLITJ 16
#define JSPAN (NB / SPLITJ)   // 512
#define NJT (JSPAN / 32)      // 16 col-tiles per block
#define GRID_MINE ((NB / 128) * SPLITJ)   // 1024 blocks

typedef __attribute__((ext_vector_type(8))) short short8;
typedef __attribute__((ext_vector_type(16))) float float16;

__device__ inline unsigned short f2bf(float f) {
    unsigned int x = __float_as_uint(f);
    unsigned int r = (x + 0x7fffu + ((x >> 16) & 1u)) >> 16;
    return (unsigned short)r;
}

// order-preserving float<->uint encode (for atomicMin/atomicMax on floats)
__device__ inline unsigned enc_f(float f) {
    unsigned u = __float_as_uint(f);
    return ((int)u < 0) ? ~u : (u | 0x80000000u);
}
__device__ inline float dec_f(unsigned u) {
    unsigned b = (u & 0x80000000u) ? (u & 0x7fffffffu) : ~u;
    return __uint_as_float(b);
}

// ---------- prep: normalize -> bf16 in MFMA-fragment order, meta, init ----------
// frag layout: for 32-row tile t, fragment ks (k-block of 16), lane l
// (half=l>>5, l31=l&31): frag[(t*8+ks)*64 + l] = row (t*32+l31),
// k = ks*16 + half*8 .. +8.  A and B operand layouts are identical (Gram).
// Block = one tile (32 rows); thread (r = tid>>3, ks = tid&7) owns 16 k's.
__global__ void prep_kernel(const float* __restrict__ emb, const int* __restrict__ labels,
                            const int* __restrict__ groups, short8* __restrict__ frag,
                            int* __restrict__ meta, unsigned* __restrict__ apu,
                            unsigned* __restrict__ anu, int* __restrict__ ticket) {
    const int t   = blockIdx.x;
    const int tid = threadIdx.x;
    const int r   = tid >> 3;          // row in tile
    const int ks  = tid & 7;           // k-fragment
    const int row = t * 32 + r;

    const float4* src = (const float4*)(emb + (size_t)row * DK + ks * 16);
    float4 q[4];
    float ss = 0.0f;
#pragma unroll
    for (int u = 0; u < 4; u++) {
        q[u] = src[u];
        ss += q[u].x * q[u].x + q[u].y * q[u].y + q[u].z * q[u].z + q[u].w * q[u].w;
    }
    // reduce across the 8 lanes sharing this row (lane = (r&7)*8 + ks)
#pragma unroll
    for (int off = 4; off; off >>= 1) ss += __shfl_xor(ss, off, 64);
    float inv = 1.0f / fmaxf(sqrtf(ss), 1e-12f);

    unsigned short h[16];
#pragma unroll
    for (int u = 0; u < 4; u++) {
        h[u * 4 + 0] = f2bf(q[u].x * inv);
        h[u * 4 + 1] = f2bf(q[u].y * inv);
        h[u * 4 + 2] = f2bf(q[u].z * inv);
        h[u * 4 + 3] = f2bf(q[u].w * inv);
    }
    short8 lo, hi;
#pragma unroll
    for (int u = 0; u < 8; u++) { lo[u] = (short)h[u]; hi[u] = (short)h[8 + u]; }
    frag[(size_t)(t * 8 + ks) * 64 + r]      = lo;   // half 0 (k offset 0..7)
    frag[(size_t)(t * 8 + ks) * 64 + 32 + r] = hi;   // half 1 (k offset 8..15)

    if (ks == 0) meta[row] = (labels[row] << 4) | groups[row];
    if (ks == 1) apu[row] = 0xFFFFFFFFu;   // +inf for min
    if (ks == 2) anu[row] = 0u;            // -inf for max
    if (t == 0 && tid == 0) *ticket = 0;
}

// ---------- barrier-free MFMA gram + mining, coalesced fragment streaming ----------
// Encoded epilogue: e = s + (same_label ? -16 : (same_group ? +4 : 0))
//   mn=min(e) -> apS = mn+16 ; mx=max(e) -> anS = mx>2 ? mx-4 : mx
//   loss = anS - mn - 15.9 ; sentinels as rounds 4-6 (verified, absmax 0.0).
// C layout (verified): col = lane&31, row = (reg&3) + 8*(reg>>2) + 4*(lane>>5)
__global__ __launch_bounds__(256, 2) void mine_mfma(
    const short8* __restrict__ frag, const int* __restrict__ meta,
    unsigned* __restrict__ apu, unsigned* __restrict__ anu,
    int* __restrict__ ticket, float* __restrict__ out) {
    const int tid  = threadIdx.x;
    const int w    = tid >> 6;
    const int lane = tid & 63;
    const int half = lane >> 5;
    const int l31  = lane & 31;
    const int irow  = blockIdx.x * 128 + w * 32;
    const int jbase = blockIdx.y * JSPAN;
    const int tA    = blockIdx.x * 4 + w;
    const int tB0   = blockIdx.y * NJT;

    // A fragments, full K=128 (8 x short8 = 64 VGPRs), coalesced loads
    short8 afrag[8];
#pragma unroll
    for (int ks = 0; ks < 8; ks++)
        afrag[ks] = frag[(size_t)(tA * 8 + ks) * 64 + lane];

    int metaI[16];
    float mn[16], mx[16];
#pragma unroll
    for (int reg = 0; reg < 16; reg++) {
        int r = (reg & 3) + 8 * (reg >> 2) + 4 * half;
        metaI[reg] = meta[irow + r];
        mn[reg] = 1e9f; mx[reg] = -1e9f;
    }

    // half-tile ping-pong: b0 = first 4 k-frags, b1 = last 4
    short8 b0[4], b1[4];
#pragma unroll
    for (int u = 0; u < 4; u++) b0[u] = frag[(size_t)(tB0 * 8 + u) * 64 + lane];
    int mj = meta[jbase + l31];

#pragma unroll 4
    for (int jt = 0; jt < NJT; jt++) {
        const int tB = tB0 + jt;
#pragma unroll
        for (int u = 0; u < 4; u++) b1[u] = frag[(size_t)(tB * 8 + 4 + u) * 64 + lane];
        int mjn = (jt + 1 < NJT) ? meta[jbase + (jt + 1) * 32 + l31] : 0;

        float16 c;
#pragma unroll
        for (int e = 0; e < 16; e++) c[e] = 0.0f;
#pragma unroll
        for (int u = 0; u < 4; u++)
            c = __builtin_amdgcn_mfma_f32_32x32x16_bf16(afrag[u], b0[u], c, 0, 0, 0);

        if (jt + 1 < NJT) {   // prefetch next tile's first half under remaining work
#pragma unroll
            for (int u = 0; u < 4; u++)
                b0[u] = frag[(size_t)((tB + 1) * 8 + u) * 64 + lane];
        }
#pragma unroll
        for (int u = 0; u < 4; u++)
            c = __builtin_amdgcn_mfma_f32_32x32x16_bf16(afrag[4 + u], b1[u], c, 0, 0, 0);

#pragma unroll
        for (int reg = 0; reg < 16; reg++) {
            float s = c[reg];
            int x = metaI[reg] ^ mj;
            bool sl = (unsigned)x < 16u;      // same label
            bool sg = (x & 15) == 0;          // same group
            float bias0 = sg ? 4.0f : 0.0f;
            float bias  = sl ? -16.0f : bias0;
            float e  = s + bias;
            mn[reg] = fminf(mn[reg], e);
            mx[reg] = fmaxf(mx[reg], e);
        }
        mj = mjn;
    }

    // butterfly reduce across the 32 column-lanes (offsets < 32 stay in-half)
#pragma unroll
    for (int reg = 0; reg < 16; reg++) {
#pragma unroll
        for (int off = 16; off; off >>= 1) {
            mn[reg] = fminf(mn[reg], __shfl_xor(mn[reg], off, 64));
            mx[reg] = fmaxf(mx[reg], __shfl_xor(mx[reg], off, 64));
        }
    }
    if (l31 == 0) {
#pragma unroll
        for (int reg = 0; reg < 16; reg++) {
            int r = (reg & 3) + 8 * (reg >> 2) + 4 * half;
            atomicMin(&apu[irow + r], enc_f(mn[reg]));
            atomicMax(&anu[irow + r], enc_f(mx[reg]));
        }
    }

    // ---------- ticketed finalize by the last-finishing block ----------
    __shared__ float ssum[4], scnt[4];
    __shared__ int lastFlag;
    __syncthreads();                      // drains this block's atomics
    if (tid == 0) {
        __threadfence();
        int old = atomicAdd(ticket, 1);   // device-scope
        lastFlag = (old == GRID_MINE - 1);
    }
    __syncthreads();
    if (!lastFlag) return;
    __threadfence();

    float s = 0.0f, ccnt = 0.0f;
#pragma unroll
    for (int k = 0; k < NB / 256; k++) {
        int i = tid + k * 256;
        float mnf = dec_f(apu[i]);
        float mxf = dec_f(anu[i]);
        float anS = (mxf > 2.0f) ? mxf - 4.0f : mxf;
        float loss = anS - mnf - 15.9f;   // anS - (mnf+16) + 0.1
        if (loss > 0.0f) { s += loss; ccnt += 1.0f; }
    }
#pragma unroll
    for (int off = 32; off; off >>= 1) {
        s    += __shfl_xor(s, off, 64);
        ccnt += __shfl_xor(ccnt, off, 64);
    }
    if (lane == 0) { ssum[w] = s; scnt[w] = ccnt; }
    __syncthreads();
    if (tid == 0) {
        float ts = 0.f, tc = 0.f;
#pragma unroll
        for (int wv = 0; wv < 4; wv++) { ts += ssum[wv]; tc += scnt[wv]; }
        float r = (tc > 0.0f) ? ts / fmaxf(tc, 1.0f) : 0.0f;
        if (isnan(r)) r = 0.0f;
        out[0] = r;
    }
}

extern "C" void kernel_launch(void* const* d_in, const int* in_sizes, int n_in,
                              void* d_out, int out_size, void* d_ws, size_t ws_size,
                              hipStream_t stream) {
    const float* emb  = (const float*)d_in[0];
    const int* labels = (const int*)d_in[1];
    const int* groups = (const int*)d_in[2];
    float* out = (float*)d_out;

    short8*   fragp  = (short8*)d_ws;                     // 2 MB (NB*DK bf16)
    int*      meta   = (int*)((char*)d_ws + (size_t)NB * DK * 2);   // 32 KB
    unsigned* apu    = (unsigned*)(meta + NB);            // 32 KB
    unsigned* anu    = apu + NB;                          // 32 KB
    int*      ticket = (int*)(anu + NB);                  // 4 B

    prep_kernel<<<NB / 32, 256, 0, stream>>>(emb, labels, groups, fragp, meta, apu, anu, ticket);
    mine_mfma<<<dim3(NB / 128, SPLITJ), 256, 0, stream>>>(fragp, meta, apu, anu, ticket, out);
}

// Round 8
// 111.315 us; speedup vs baseline: 1.0660x; 1.0660x over previous
//
#include <hip/hip_runtime.h>
#include <math.h>

#define NB 8192
#define DK 128
#define SPLITJ 16
#define JSPAN (NB / SPLITJ)   // 512
#define NJT (JSPAN / 32)      // 16 col-tiles per block
#define GRID_MINE ((NB / 128) * SPLITJ)   // 1024 blocks

typedef __attribute__((ext_vector_type(8))) short short8;
typedef __attribute__((ext_vector_type(16))) float float16;

__device__ inline unsigned short f2bf(float f) {
    unsigned int x = __float_as_uint(f);
    unsigned int r = (x + 0x7fffu + ((x >> 16) & 1u)) >> 16;
    return (unsigned short)r;
}

// order-preserving float<->uint encode (for atomicMin/atomicMax on floats)
__device__ inline unsigned enc_f(float f) {
    unsigned u = __float_as_uint(f);
    return ((int)u < 0) ? ~u : (u | 0x80000000u);
}
__device__ inline float dec_f(unsigned u) {
    unsigned b = (u & 0x80000000u) ? (u & 0x7fffffffu) : ~u;
    return __uint_as_float(b);
}

// bias encode (same semantics as rounds 4-7, verified absmax 0.0):
// e = s + (same_label ? -16 : (same_group ? +4 : 0))
__device__ inline float biasf(int mi, int mj) {
    int x = mi ^ mj;
    bool sl = (unsigned)x < 16u;     // same label
    bool sg = (x & 15) == 0;         // same group
    float b0 = sg ? 4.0f : 0.0f;
    return sl ? -16.0f : b0;
}

// ---------- prep: normalize -> bf16 in MFMA-fragment order, meta, init ----------
// frag layout: for 32-row tile t, fragment ks, lane l: frag[(t*8+ks)*64 + l]
// = row (t*32 + (l&31)), k = ks*16 + (l>>5)*8 .. +8.  (verified round 7)
__global__ void prep_kernel(const float* __restrict__ emb, const int* __restrict__ labels,
                            const int* __restrict__ groups, short8* __restrict__ frag,
                            int* __restrict__ meta, unsigned* __restrict__ apu,
                            unsigned* __restrict__ anu, int* __restrict__ ticket) {
    const int t   = blockIdx.x;
    const int tid = threadIdx.x;
    const int r   = tid >> 3;          // row in tile
    const int ks  = tid & 7;           // k-fragment
    const int row = t * 32 + r;

    const float4* src = (const float4*)(emb + (size_t)row * DK + ks * 16);
    float4 q[4];
    float ss = 0.0f;
#pragma unroll
    for (int u = 0; u < 4; u++) {
        q[u] = src[u];
        ss += q[u].x * q[u].x + q[u].y * q[u].y + q[u].z * q[u].z + q[u].w * q[u].w;
    }
#pragma unroll
    for (int off = 4; off; off >>= 1) ss += __shfl_xor(ss, off, 64);
    float inv = 1.0f / fmaxf(sqrtf(ss), 1e-12f);

    unsigned short h[16];
#pragma unroll
    for (int u = 0; u < 4; u++) {
        h[u * 4 + 0] = f2bf(q[u].x * inv);
        h[u * 4 + 1] = f2bf(q[u].y * inv);
        h[u * 4 + 2] = f2bf(q[u].z * inv);
        h[u * 4 + 3] = f2bf(q[u].w * inv);
    }
    short8 lo, hi;
#pragma unroll
    for (int u = 0; u < 8; u++) { lo[u] = (short)h[u]; hi[u] = (short)h[8 + u]; }
    frag[(size_t)(t * 8 + ks) * 64 + r]      = lo;
    frag[(size_t)(t * 8 + ks) * 64 + 32 + r] = hi;

    if (ks == 0) meta[row] = (labels[row] << 4) | groups[row];
    if (ks == 1) apu[row] = 0xFFFFFFFFu;   // +inf for min
    if (ks == 2) anu[row] = 0u;            // -inf for max
    if (t == 0 && tid == 0) *ticket = 0;
}

// ---------- barrier-free MFMA gram + mining, 2-deep software pipeline ----------
// grid (SPLITJ, NB/128): x fastest-varying -> co-resident blocks share B-stream.
// Accumulator initialized to bias -> epilogue is min+max only.
// C layout (verified): col = lane&31, row = (reg&3) + 8*(reg>>2) + 4*(lane>>5)
__global__ __launch_bounds__(256, 2) void mine_mfma(
    const short8* __restrict__ frag, const int* __restrict__ meta,
    unsigned* __restrict__ apu, unsigned* __restrict__ anu,
    int* __restrict__ ticket, float* __restrict__ out) {
    const int tid  = threadIdx.x;
    const int w    = tid >> 6;
    const int lane = tid & 63;
    const int half = lane >> 5;
    const int l31  = lane & 31;
    const int irow  = blockIdx.y * 128 + w * 32;
    const int jbase = blockIdx.x * JSPAN;
    const int tA    = blockIdx.y * 4 + w;
    const int tB0   = blockIdx.x * NJT;

    // A fragments, full K=128 (8 x short8), coalesced
    short8 afrag[8];
#pragma unroll
    for (int ks = 0; ks < 8; ks++)
        afrag[ks] = frag[(size_t)(tA * 8 + ks) * 64 + lane];

    int metaI[16];
    float mn[16], mx[16];
#pragma unroll
    for (int reg = 0; reg < 16; reg++) {
        int r = (reg & 3) + 8 * (reg >> 2) + 4 * half;
        metaI[reg] = meta[irow + r];
        mn[reg] = 1e9f; mx[reg] = -1e9f;
    }

    // 2-deep pipeline state
    short8  bb[2][8];
    float16 cc[2];

    // prologue: tile 0 fragments + bias-initialized accumulator
#pragma unroll
    for (int u = 0; u < 8; u++) bb[0][u] = frag[(size_t)(tB0 * 8 + u) * 64 + lane];
    {
        int mj = meta[jbase + l31];
#pragma unroll
        for (int reg = 0; reg < 16; reg++) cc[0][reg] = biasf(metaI[reg], mj);
    }

#pragma unroll 2
    for (int jt = 0; jt < NJT; jt++) {
        const int cur = jt & 1;

        // issue next tile's loads + bias init first (independent of current chain)
        if (jt + 1 < NJT) {
            const int tBn = tB0 + jt + 1;
#pragma unroll
            for (int u = 0; u < 8; u++)
                bb[cur ^ 1][u] = frag[(size_t)(tBn * 8 + u) * 64 + lane];
            int mjn = meta[jbase + (jt + 1) * 32 + l31];
#pragma unroll
            for (int reg = 0; reg < 16; reg++)
                cc[cur ^ 1][reg] = biasf(metaI[reg], mjn);
        }

        // MFMA chain for current tile (accumulates s onto the bias)
#pragma unroll
        for (int u = 0; u < 8; u++)
            cc[cur] = __builtin_amdgcn_mfma_f32_32x32x16_bf16(afrag[u], bb[cur][u], cc[cur], 0, 0, 0);

        // epilogue: min + max only
#pragma unroll
        for (int reg = 0; reg < 16; reg++) {
            mn[reg] = fminf(mn[reg], cc[cur][reg]);
            mx[reg] = fmaxf(mx[reg], cc[cur][reg]);
        }
    }

    // butterfly reduce across the 32 column-lanes (offsets < 32 stay in-half)
#pragma unroll
    for (int reg = 0; reg < 16; reg++) {
#pragma unroll
        for (int off = 16; off; off >>= 1) {
            mn[reg] = fminf(mn[reg], __shfl_xor(mn[reg], off, 64));
            mx[reg] = fmaxf(mx[reg], __shfl_xor(mx[reg], off, 64));
        }
    }
    if (l31 == 0) {
#pragma unroll
        for (int reg = 0; reg < 16; reg++) {
            int r = (reg & 3) + 8 * (reg >> 2) + 4 * half;
            atomicMin(&apu[irow + r], enc_f(mn[reg]));
            atomicMax(&anu[irow + r], enc_f(mx[reg]));
        }
    }

    // ---------- ticketed finalize by the last-finishing block ----------
    __shared__ float ssum[4], scnt[4];
    __shared__ int lastFlag;
    __syncthreads();                      // drains this block's atomics
    if (tid == 0) {
        __threadfence();
        int old = atomicAdd(ticket, 1);   // device-scope
        lastFlag = (old == GRID_MINE - 1);
    }
    __syncthreads();
    if (!lastFlag) return;
    __threadfence();

    float s = 0.0f, ccnt = 0.0f;
#pragma unroll
    for (int k = 0; k < NB / 256; k++) {
        int i = tid + k * 256;
        float mnf = dec_f(apu[i]);
        float mxf = dec_f(anu[i]);
        float anS = (mxf > 2.0f) ? mxf - 4.0f : mxf;
        float loss = anS - mnf - 15.9f;   // anS - (mnf+16) + 0.1
        if (loss > 0.0f) { s += loss; ccnt += 1.0f; }
    }
#pragma unroll
    for (int off = 32; off; off >>= 1) {
        s    += __shfl_xor(s, off, 64);
        ccnt += __shfl_xor(ccnt, off, 64);
    }
    if (lane == 0) { ssum[w] = s; scnt[w] = ccnt; }
    __syncthreads();
    if (tid == 0) {
        float ts = 0.f, tc = 0.f;
#pragma unroll
        for (int wv = 0; wv < 4; wv++) { ts += ssum[wv]; tc += scnt[wv]; }
        float r = (tc > 0.0f) ? ts / fmaxf(tc, 1.0f) : 0.0f;
        if (isnan(r)) r = 0.0f;
        out[0] = r;
    }
}

extern "C" void kernel_launch(void* const* d_in, const int* in_sizes, int n_in,
                              void* d_out, int out_size, void* d_ws, size_t ws_size,
                              hipStream_t stream) {
    const float* emb  = (const float*)d_in[0];
    const int* labels = (const int*)d_in[1];
    const int* groups = (const int*)d_in[2];
    float* out = (float*)d_out;

    short8*   fragp  = (short8*)d_ws;                               // 2 MB
    int*      meta   = (int*)((char*)d_ws + (size_t)NB * DK * 2);   // 32 KB
    unsigned* apu    = (unsigned*)(meta + NB);                      // 32 KB
    unsigned* anu    = apu + NB;                                    // 32 KB
    int*      ticket = (int*)(anu + NB);                            // 4 B

    prep_kernel<<<NB / 32, 256, 0, stream>>>(emb, labels, groups, fragp, meta, apu, anu, ticket);
    mine_mfma<<<dim3(SPLITJ, NB / 128), 256, 0, stream>>>(fragp, meta, apu, anu, ticket, out);
}